// Round 1
// baseline (242.524 us; speedup 1.0000x reference)
//
#include <hip/hip_runtime.h>
#include <math.h>

// ExpertGating: h=relu(hs@W1+b1); logits=h@W2+b2; softmax; top-2; combine expert outputs.
// B=4,S=2048 -> M=8192 tokens; H=1024; E=8; k=2.
// Round 1: all-fp32 correctness-first. GEMM1 = classic SGEMM (128x128 tile, 8x8/thread).
// h is materialized into d_out; kernel 2 reads its own row then overwrites it in place.

#define H_DIM 1024
#define E_NUM 8
#define BM 128
#define BN 128
#define BK 16
#define PAD_LD 132   // padded LDS row (floats): keeps 16B alignment, breaks bank conflicts

__global__ __launch_bounds__(256) void gemm1_relu_kernel(
    const float* __restrict__ A,    // [M, K] hidden_states
    const float* __restrict__ W,    // [K, N] W1
    const float* __restrict__ bias, // [N]
    float* __restrict__ Hout,       // [M, N]
    int M, int N, int K)
{
    __shared__ float As[BK][PAD_LD];  // A-tile transposed: As[k][m]
    __shared__ float Bs[BK][PAD_LD];  // B-tile: Bs[k][n]

    const int tid = threadIdx.x;
    const int tx = tid & 15;   // n-dir thread coord
    const int ty = tid >> 4;   // m-dir thread coord
    const int row0 = blockIdx.y * BM;
    const int col0 = blockIdx.x * BN;

    float acc[8][8];
    #pragma unroll
    for (int i = 0; i < 8; ++i)
        #pragma unroll
        for (int j = 0; j < 8; ++j) acc[i][j] = 0.f;

    // A-load mapping: 2 x float4 per thread (rows tid/4 and tid/4+64, k-quad tid%4)
    const int a_row = tid >> 2;        // 0..63
    const int a_k4  = (tid & 3) * 4;   // 0,4,8,12
    // B-load mapping: 2 x float4 per thread (k rows tid/32 and +8, col-quad tid%32)
    const int b_col4 = (tid & 31) * 4; // 0..124
    const int b_kk   = tid >> 5;       // 0..7

    for (int k0 = 0; k0 < K; k0 += BK) {
        #pragma unroll
        for (int half = 0; half < 2; ++half) {
            int r = a_row + half * 64;
            float4 av = *reinterpret_cast<const float4*>(
                &A[(size_t)(row0 + r) * K + k0 + a_k4]);
            As[a_k4 + 0][r] = av.x;
            As[a_k4 + 1][r] = av.y;
            As[a_k4 + 2][r] = av.z;
            As[a_k4 + 3][r] = av.w;
        }
        #pragma unroll
        for (int half = 0; half < 2; ++half) {
            int kk = b_kk + half * 8;
            float4 bv = *reinterpret_cast<const float4*>(
                &W[(size_t)(k0 + kk) * N + col0 + b_col4]);
            *reinterpret_cast<float4*>(&Bs[kk][b_col4]) = bv;
        }
        __syncthreads();

        #pragma unroll
        for (int k = 0; k < BK; ++k) {
            float4 a0 = *reinterpret_cast<const float4*>(&As[k][ty * 8]);
            float4 a1 = *reinterpret_cast<const float4*>(&As[k][ty * 8 + 4]);
            float4 b0 = *reinterpret_cast<const float4*>(&Bs[k][tx * 8]);
            float4 b1 = *reinterpret_cast<const float4*>(&Bs[k][tx * 8 + 4]);
            float a[8] = {a0.x, a0.y, a0.z, a0.w, a1.x, a1.y, a1.z, a1.w};
            float b[8] = {b0.x, b0.y, b0.z, b0.w, b1.x, b1.y, b1.z, b1.w};
            #pragma unroll
            for (int i = 0; i < 8; ++i)
                #pragma unroll
                for (int j = 0; j < 8; ++j)
                    acc[i][j] = fmaf(a[i], b[j], acc[i][j]);
        }
        __syncthreads();
    }

    // epilogue: bias + relu, vectorized store
    #pragma unroll
    for (int i = 0; i < 8; ++i) {
        int row = row0 + ty * 8 + i;
        #pragma unroll
        for (int j4 = 0; j4 < 2; ++j4) {
            int col = col0 + tx * 8 + j4 * 4;
            float4 v;
            v.x = fmaxf(acc[i][j4 * 4 + 0] + bias[col + 0], 0.f);
            v.y = fmaxf(acc[i][j4 * 4 + 1] + bias[col + 1], 0.f);
            v.z = fmaxf(acc[i][j4 * 4 + 2] + bias[col + 2], 0.f);
            v.w = fmaxf(acc[i][j4 * 4 + 3] + bias[col + 3], 0.f);
            *reinterpret_cast<float4*>(&Hout[(size_t)row * N + col]) = v;
        }
    }
}

// One block per token. Phase A: logits = h@W2+b2 (block reduce), softmax, top-2.
// Phase B: out = g0*EO[e0] + g1*EO[e1]. Reads h row then overwrites it (same buffer).
__global__ __launch_bounds__(256) void route_combine_kernel(
    const float* __restrict__ Hbuf, // [M, H]  (aliases Out)
    const float* __restrict__ W2,   // [H, E]
    const float* __restrict__ b2,   // [E]
    const float* __restrict__ EO,   // [E, M, H]
    float* __restrict__ Out,        // [M, H]
    int M)
{
    const int t = blockIdx.x;
    const int tid = threadIdx.x;
    const int lane = tid & 63;
    const int wave = tid >> 6;

    const float* hrow = Hbuf + (size_t)t * H_DIM;

    float part[E_NUM];
    #pragma unroll
    for (int e = 0; e < E_NUM; ++e) part[e] = 0.f;

    #pragma unroll
    for (int it = 0; it < H_DIM / 256; ++it) {
        int j = tid + it * 256;
        float hv = hrow[j];
        const float* w = W2 + (size_t)j * E_NUM;
        #pragma unroll
        for (int e = 0; e < E_NUM; ++e) part[e] = fmaf(hv, w[e], part[e]);
    }

    // wave-level butterfly reduce (64 lanes)
    #pragma unroll
    for (int off = 32; off > 0; off >>= 1) {
        #pragma unroll
        for (int e = 0; e < E_NUM; ++e)
            part[e] += __shfl_down(part[e], off, 64);
    }

    __shared__ float sred[4][E_NUM];
    __shared__ float s_g[2];
    __shared__ int   s_e[2];
    if (lane == 0) {
        #pragma unroll
        for (int e = 0; e < E_NUM; ++e) sred[wave][e] = part[e];
    }
    __syncthreads();

    if (tid == 0) {
        float logits[E_NUM];
        #pragma unroll
        for (int e = 0; e < E_NUM; ++e)
            logits[e] = sred[0][e] + sred[1][e] + sred[2][e] + sred[3][e] + b2[e];
        float m = logits[0];
        #pragma unroll
        for (int e = 1; e < E_NUM; ++e) m = fmaxf(m, logits[e]);
        float p[E_NUM], s = 0.f;
        #pragma unroll
        for (int e = 0; e < E_NUM; ++e) { p[e] = expf(logits[e] - m); s += p[e]; }
        float inv = 1.f / s;
        #pragma unroll
        for (int e = 0; e < E_NUM; ++e) p[e] *= inv;   // router_probs
        // top-2 with lowest-index tie-break (matches jax.lax.top_k)
        int e0 = 0;
        #pragma unroll
        for (int e = 1; e < E_NUM; ++e) if (p[e] > p[e0]) e0 = e;
        int e1 = (e0 == 0) ? 1 : 0;
        #pragma unroll
        for (int e = 0; e < E_NUM; ++e)
            if (e != e0 && e != e1 && p[e] > p[e1]) e1 = e;
        s_g[0] = p[e0]; s_g[1] = p[e1];
        s_e[0] = e0;    s_e[1] = e1;
    }
    __syncthreads();

    const float g0 = s_g[0], g1 = s_g[1];
    const size_t base0 = ((size_t)s_e[0] * M + t) * H_DIM;
    const size_t base1 = ((size_t)s_e[1] * M + t) * H_DIM;
    const int d = tid * 4;  // 256 threads * 4 floats = 1024 = H_DIM

    float4 x0 = *reinterpret_cast<const float4*>(&EO[base0 + d]);
    float4 x1 = *reinterpret_cast<const float4*>(&EO[base1 + d]);
    float4 o;
    o.x = g0 * x0.x + g1 * x1.x;
    o.y = g0 * x0.y + g1 * x1.y;
    o.z = g0 * x0.z + g1 * x1.z;
    o.w = g0 * x0.w + g1 * x1.w;
    *reinterpret_cast<float4*>(&Out[(size_t)t * H_DIM + d]) = o;
}

extern "C" void kernel_launch(void* const* d_in, const int* in_sizes, int n_in,
                              void* d_out, int out_size, void* d_ws, size_t ws_size,
                              hipStream_t stream)
{
    const float* hs = (const float*)d_in[0];  // [B,S,H]
    const float* EO = (const float*)d_in[1];  // [E,B,S,H]
    const float* W1 = (const float*)d_in[2];  // [H,H]
    const float* b1 = (const float*)d_in[3];  // [H]
    const float* W2 = (const float*)d_in[4];  // [H,E]
    const float* b2 = (const float*)d_in[5];  // [E]
    // d_in[6] = k (always 2 for this problem; kernel hardcodes top-2)

    const int M = in_sizes[0] / H_DIM;  // B*S = 8192
    float* out = (float*)d_out;

    dim3 grid1(H_DIM / BN, M / BM);  // (8, 64)
    gemm1_relu_kernel<<<grid1, 256, 0, stream>>>(hs, W1, b1, out, M, H_DIM, H_DIM);
    route_combine_kernel<<<M, 256, 0, stream>>>(out, W2, b2, EO, out, M);
}

// Round 2
// 88.100 us; speedup vs baseline: 2.7528x; 2.7528x over previous
//
#include <hip/hip_runtime.h>
#include <math.h>

// ExpertGating: h=relu(hs@W1+b1); logits=h@W2+b2; softmax; top-2; combine.
// R2: GEMM1 via split-bf16 3-pass MFMA (error ~2^-18 rel, keeps top-2 selection exact).
//  - prep kernels write hi/lo bf16 *pre-swizzled LDS images* into d_ws
//  - gemm stages with global_load_lds(16B) into linear LDS (swizzle baked in source)
//  - ds_read_b128 fragment reads XOR-swizzled -> uniform 8 lanes/bank-quad (conflict-free)
// Fallback to the verified R1 fp32 SGEMM if ws_size is too small.

#define H_DIM 1024
#define E_NUM 8

typedef __attribute__((ext_vector_type(8))) short s16x8;          // 8 bf16 (4 VGPR)
typedef __attribute__((ext_vector_type(8))) unsigned short u16x8;
typedef __attribute__((ext_vector_type(4))) float f32x4;

__device__ __forceinline__ unsigned short f2bf(float x) {
    // round-to-nearest-even bf16
    unsigned int u = __float_as_uint(x);
    unsigned int r = (u + 0x7FFFu + ((u >> 16) & 1u)) >> 16;
    return (unsigned short)r;
}
__device__ __forceinline__ float bf2f(unsigned short b) {
    return __uint_as_float(((unsigned int)b) << 16);
}

__device__ __forceinline__ void gload_lds16(const void* g, void* lds) {
    __builtin_amdgcn_global_load_lds(
        (const __attribute__((address_space(1))) void*)g,
        (__attribute__((address_space(3))) void*)lds, 16, 0, 0);
}

// ---------------- prep: hs -> swizzled hi/lo bf16 image ----------------
// Image layout: [rb(64)][kt(32)] tiles of 16384 B; tile = 128 rows x 128 B.
// Row mr: 8 slots of 16 B. Logical slot s (0-3 = hi k-octets, 4-7 = lo) stored
// at physical slot s ^ (mr&7).
__global__ __launch_bounds__(256) void prep_a_kernel(
    const float* __restrict__ A, char* __restrict__ img)
{
    int t = blockIdx.x * 256 + threadIdx.x;   // 1M threads: 8192 rows x 128 octets
    int m = t >> 7;
    int k = (t & 127) << 3;
    const float* src = A + ((size_t)m << 10) + k;
    float4 v0 = *reinterpret_cast<const float4*>(src);
    float4 v1 = *reinterpret_cast<const float4*>(src + 4);
    float xs[8] = {v0.x, v0.y, v0.z, v0.w, v1.x, v1.y, v1.z, v1.w};
    u16x8 hv, lv;
    #pragma unroll
    for (int j = 0; j < 8; ++j) {
        unsigned short h = f2bf(xs[j]);
        hv[j] = h;
        lv[j] = f2bf(xs[j] - bf2f(h));
    }
    int rb = m >> 7, mr = m & 127, kt = k >> 5, s = (k >> 3) & 3;
    char* base = img + (((size_t)(rb * 32 + kt)) << 14) + mr * 128;
    *reinterpret_cast<u16x8*>(base + ((s ^ (mr & 7)) << 4)) = hv;
    *reinterpret_cast<u16x8*>(base + (((s + 4) ^ (mr & 7)) << 4)) = lv;
}

// W1[k][n] -> transposed swizzled image: [cb(8)][kt(32)] tiles; tile row = col n.
__global__ __launch_bounds__(256) void prep_b_kernel(
    const float* __restrict__ W, char* __restrict__ img)
{
    int t = blockIdx.x * 256 + threadIdx.x;   // 131072 threads: 1024 cols x 128 octets
    int n = t & 1023;
    int k = (t >> 10) << 3;
    u16x8 hv, lv;
    #pragma unroll
    for (int j = 0; j < 8; ++j) {
        float x = W[((size_t)(k + j) << 10) + n];   // coalesced across lanes (consecutive n)
        unsigned short h = f2bf(x);
        hv[j] = h;
        lv[j] = f2bf(x - bf2f(h));
    }
    int cb = n >> 7, nr = n & 127, kt = k >> 5, s = (k >> 3) & 3;
    char* base = img + (((size_t)(cb * 32 + kt)) << 14) + nr * 128;
    *reinterpret_cast<u16x8*>(base + ((s ^ (nr & 7)) << 4)) = hv;
    *reinterpret_cast<u16x8*>(base + (((s + 4) ^ (nr & 7)) << 4)) = lv;
}

// ---------------- GEMM1: 128x128 tile, 4 waves (2x2 of 64x64), BK=32 ----------------
__global__ __launch_bounds__(256, 2) void gemm1_mfma_kernel(
    const char* __restrict__ Aimg, const char* __restrict__ Bimg,
    const float* __restrict__ bias, float* __restrict__ Hout)
{
    __shared__ char As[16384];
    __shared__ char Bs[16384];

    int bid = blockIdx.x;
    // XCD-aware bijective swizzle: 512 blocks, 8 XCDs, 64 consecutive per XCD
    int swz = (bid & 7) * 64 + (bid >> 3);
    int rb = swz >> 3;          // 0..63
    int cb = swz & 7;           // 0..7

    int tid = threadIdx.x;
    int lane = tid & 63;
    int wave = tid >> 6;
    int wm = (wave >> 1) * 64;
    int wn = (wave & 1) * 64;
    int l15 = lane & 15, l4 = lane >> 4;

    // precomputed swizzled fragment offsets (constant across K-tiles)
    int aoff_h[4], aoff_l[4], boff_h[4], boff_l[4];
    #pragma unroll
    for (int f = 0; f < 4; ++f) {
        int ar = wm + f * 16 + l15;
        aoff_h[f] = ar * 128 + ((l4 ^ (ar & 7)) << 4);
        aoff_l[f] = ar * 128 + (((l4 + 4) ^ (ar & 7)) << 4);
        int br = wn + f * 16 + l15;
        boff_h[f] = br * 128 + ((l4 ^ (br & 7)) << 4);
        boff_l[f] = br * 128 + (((l4 + 4) ^ (br & 7)) << 4);
    }

    const char* abase = Aimg + (size_t)rb * (32 * 16384);
    const char* bbase = Bimg + (size_t)cb * (32 * 16384);

    f32x4 acc[4][4];
    #pragma unroll
    for (int i = 0; i < 4; ++i)
        #pragma unroll
        for (int j = 0; j < 4; ++j)
            acc[i][j] = (f32x4){0.f, 0.f, 0.f, 0.f};

    for (int kt = 0; kt < 32; ++kt) {
        const char* ga = abase + (kt << 14);
        const char* gb = bbase + (kt << 14);
        int toff = tid << 4;
        #pragma unroll
        for (int r = 0; r < 4; ++r) {
            gload_lds16(ga + (r << 12) + toff, As + (r << 12) + toff);
            gload_lds16(gb + (r << 12) + toff, Bs + (r << 12) + toff);
        }
        __syncthreads();   // compiler emits vmcnt(0) drain -> tiles ready

        s16x8 ah[4], al[4], bh[4], bl[4];
        #pragma unroll
        for (int f = 0; f < 4; ++f) {
            ah[f] = *reinterpret_cast<const s16x8*>(As + aoff_h[f]);
            al[f] = *reinterpret_cast<const s16x8*>(As + aoff_l[f]);
            bh[f] = *reinterpret_cast<const s16x8*>(Bs + boff_h[f]);
            bl[f] = *reinterpret_cast<const s16x8*>(Bs + boff_l[f]);
        }
        #pragma unroll
        for (int m = 0; m < 4; ++m)
            #pragma unroll
            for (int n = 0; n < 4; ++n) {
                acc[m][n] = __builtin_amdgcn_mfma_f32_16x16x32_bf16(ah[m], bh[n], acc[m][n], 0, 0, 0);
                acc[m][n] = __builtin_amdgcn_mfma_f32_16x16x32_bf16(ah[m], bl[n], acc[m][n], 0, 0, 0);
                acc[m][n] = __builtin_amdgcn_mfma_f32_16x16x32_bf16(al[m], bh[n], acc[m][n], 0, 0, 0);
            }
        __syncthreads();   // all waves done reading before next stage overwrites
    }

    // epilogue: bias + relu. C/D map: row=(lane>>4)*4+reg, col=lane&15 (m89)
    int row0 = rb * 128 + wm;
    int col0 = cb * 128 + wn;
    float bcol[4];
    #pragma unroll
    for (int fn = 0; fn < 4; ++fn) bcol[fn] = bias[col0 + fn * 16 + l15];
    #pragma unroll
    for (int fm = 0; fm < 4; ++fm)
        #pragma unroll
        for (int r = 0; r < 4; ++r) {
            int row = row0 + fm * 16 + l4 * 4 + r;
            float* orow = Hout + ((size_t)row << 10);
            #pragma unroll
            for (int fn = 0; fn < 4; ++fn) {
                int col = col0 + fn * 16 + l15;
                orow[col] = fmaxf(acc[fm][fn][r] + bcol[fn], 0.f);
            }
        }
}

// ---------------- R1 fallback fp32 SGEMM (verified) ----------------
#define BM 128
#define BN 128
#define BK 16
#define PAD_LD 132

__global__ __launch_bounds__(256) void gemm1_relu_kernel(
    const float* __restrict__ A, const float* __restrict__ W,
    const float* __restrict__ bias, float* __restrict__ Hout,
    int M, int N, int K)
{
    __shared__ float As[BK][PAD_LD];
    __shared__ float Bs[BK][PAD_LD];
    const int tid = threadIdx.x;
    const int tx = tid & 15;
    const int ty = tid >> 4;
    const int row0 = blockIdx.y * BM;
    const int col0 = blockIdx.x * BN;
    float acc[8][8];
    #pragma unroll
    for (int i = 0; i < 8; ++i)
        #pragma unroll
        for (int j = 0; j < 8; ++j) acc[i][j] = 0.f;
    const int a_row = tid >> 2;
    const int a_k4  = (tid & 3) * 4;
    const int b_col4 = (tid & 31) * 4;
    const int b_kk   = tid >> 5;
    for (int k0 = 0; k0 < K; k0 += BK) {
        #pragma unroll
        for (int half = 0; half < 2; ++half) {
            int r = a_row + half * 64;
            float4 av = *reinterpret_cast<const float4*>(&A[(size_t)(row0 + r) * K + k0 + a_k4]);
            As[a_k4 + 0][r] = av.x; As[a_k4 + 1][r] = av.y;
            As[a_k4 + 2][r] = av.z; As[a_k4 + 3][r] = av.w;
        }
        #pragma unroll
        for (int half = 0; half < 2; ++half) {
            int kk = b_kk + half * 8;
            float4 bv = *reinterpret_cast<const float4*>(&W[(size_t)(k0 + kk) * N + col0 + b_col4]);
            *reinterpret_cast<float4*>(&Bs[kk][b_col4]) = bv;
        }
        __syncthreads();
        #pragma unroll
        for (int k = 0; k < BK; ++k) {
            float4 a0 = *reinterpret_cast<const float4*>(&As[k][ty * 8]);
            float4 a1 = *reinterpret_cast<const float4*>(&As[k][ty * 8 + 4]);
            float4 b0 = *reinterpret_cast<const float4*>(&Bs[k][tx * 8]);
            float4 b1 = *reinterpret_cast<const float4*>(&Bs[k][tx * 8 + 4]);
            float a[8] = {a0.x, a0.y, a0.z, a0.w, a1.x, a1.y, a1.z, a1.w};
            float b[8] = {b0.x, b0.y, b0.z, b0.w, b1.x, b1.y, b1.z, b1.w};
            #pragma unroll
            for (int i = 0; i < 8; ++i)
                #pragma unroll
                for (int j = 0; j < 8; ++j)
                    acc[i][j] = fmaf(a[i], b[j], acc[i][j]);
        }
        __syncthreads();
    }
    #pragma unroll
    for (int i = 0; i < 8; ++i) {
        int row = row0 + ty * 8 + i;
        #pragma unroll
        for (int j4 = 0; j4 < 2; ++j4) {
            int col = col0 + tx * 8 + j4 * 4;
            float4 v;
            v.x = fmaxf(acc[i][j4 * 4 + 0] + bias[col + 0], 0.f);
            v.y = fmaxf(acc[i][j4 * 4 + 1] + bias[col + 1], 0.f);
            v.z = fmaxf(acc[i][j4 * 4 + 2] + bias[col + 2], 0.f);
            v.w = fmaxf(acc[i][j4 * 4 + 3] + bias[col + 3], 0.f);
            *reinterpret_cast<float4*>(&Hout[(size_t)row * N + col]) = v;
        }
    }
}

// ---------------- router + combine (one block per token) ----------------
__global__ __launch_bounds__(256) void route_combine_kernel(
    const float* __restrict__ Hbuf, const float* __restrict__ W2,
    const float* __restrict__ b2, const float* __restrict__ EO,
    float* __restrict__ Out, int M)
{
    const int t = blockIdx.x;
    const int tid = threadIdx.x;
    const int lane = tid & 63;
    const int wave = tid >> 6;
    const float* hrow = Hbuf + (size_t)t * H_DIM;

    float part[E_NUM];
    #pragma unroll
    for (int e = 0; e < E_NUM; ++e) part[e] = 0.f;
    #pragma unroll
    for (int it = 0; it < H_DIM / 256; ++it) {
        int j = tid + it * 256;
        float hv = hrow[j];
        const float* w = W2 + (size_t)j * E_NUM;
        #pragma unroll
        for (int e = 0; e < E_NUM; ++e) part[e] = fmaf(hv, w[e], part[e]);
    }
    #pragma unroll
    for (int off = 32; off > 0; off >>= 1)
        #pragma unroll
        for (int e = 0; e < E_NUM; ++e)
            part[e] += __shfl_down(part[e], off, 64);

    __shared__ float sred[4][E_NUM];
    __shared__ float s_g[2];
    __shared__ int   s_e[2];
    if (lane == 0)
        #pragma unroll
        for (int e = 0; e < E_NUM; ++e) sred[wave][e] = part[e];
    __syncthreads();

    if (tid == 0) {
        float logits[E_NUM];
        #pragma unroll
        for (int e = 0; e < E_NUM; ++e)
            logits[e] = sred[0][e] + sred[1][e] + sred[2][e] + sred[3][e] + b2[e];
        float m = logits[0];
        #pragma unroll
        for (int e = 1; e < E_NUM; ++e) m = fmaxf(m, logits[e]);
        float p[E_NUM], ssum = 0.f;
        #pragma unroll
        for (int e = 0; e < E_NUM; ++e) { p[e] = expf(logits[e] - m); ssum += p[e]; }
        float inv = 1.f / ssum;
        #pragma unroll
        for (int e = 0; e < E_NUM; ++e) p[e] *= inv;
        int e0 = 0;
        #pragma unroll
        for (int e = 1; e < E_NUM; ++e) if (p[e] > p[e0]) e0 = e;
        int e1 = (e0 == 0) ? 1 : 0;
        #pragma unroll
        for (int e = 0; e < E_NUM; ++e)
            if (e != e0 && e != e1 && p[e] > p[e1]) e1 = e;
        s_g[0] = p[e0]; s_g[1] = p[e1];
        s_e[0] = e0;    s_e[1] = e1;
    }
    __syncthreads();

    const float g0 = s_g[0], g1 = s_g[1];
    const size_t base0 = ((size_t)s_e[0] * M + t) * H_DIM;
    const size_t base1 = ((size_t)s_e[1] * M + t) * H_DIM;
    const int d = tid * 4;
    float4 x0 = *reinterpret_cast<const float4*>(&EO[base0 + d]);
    float4 x1 = *reinterpret_cast<const float4*>(&EO[base1 + d]);
    float4 o;
    o.x = g0 * x0.x + g1 * x1.x;
    o.y = g0 * x0.y + g1 * x1.y;
    o.z = g0 * x0.z + g1 * x1.z;
    o.w = g0 * x0.w + g1 * x1.w;
    *reinterpret_cast<float4*>(&Out[(size_t)t * H_DIM + d]) = o;
}

extern "C" void kernel_launch(void* const* d_in, const int* in_sizes, int n_in,
                              void* d_out, int out_size, void* d_ws, size_t ws_size,
                              hipStream_t stream)
{
    const float* hs = (const float*)d_in[0];
    const float* EO = (const float*)d_in[1];
    const float* W1 = (const float*)d_in[2];
    const float* b1 = (const float*)d_in[3];
    const float* W2 = (const float*)d_in[4];
    const float* b2 = (const float*)d_in[5];

    const int M = in_sizes[0] / H_DIM;   // 8192
    float* out = (float*)d_out;

    const size_t A_IMG = (size_t)64 * 32 * 16384;        // 33,554,432
    const size_t B_IMG = (size_t)8 * 32 * 16384;         //  4,194,304
    if (M == 8192 && ws_size >= A_IMG + B_IMG) {
        char* Aimg = (char*)d_ws;
        char* Bimg = (char*)d_ws + A_IMG;
        prep_a_kernel<<<4096, 256, 0, stream>>>(hs, Aimg);
        prep_b_kernel<<<512, 256, 0, stream>>>(W1, Bimg);
        gemm1_mfma_kernel<<<512, 256, 0, stream>>>(Aimg, Bimg, b1, out);
    } else {
        dim3 grid1(H_DIM / BN, M / BM);
        gemm1_relu_kernel<<<grid1, 256, 0, stream>>>(hs, W1, b1, out, M, H_DIM, H_DIM);
    }
    route_combine_kernel<<<M, 256, 0, stream>>>(out, W2, b2, EO, out, M);
}